// Round 3
// baseline (1058.882 us; speedup 1.0000x reference)
//
#include <hip/hip_runtime.h>
#include <hip/hip_bf16.h>
#include <hip/hip_cooperative_groups.h>

namespace cg = cooperative_groups;

typedef unsigned short u16;
typedef float f32x4 __attribute__((ext_vector_type(4)));
typedef u16   u16x8 __attribute__((ext_vector_type(8)));
typedef u16   u16x4 __attribute__((ext_vector_type(4)));
typedef short s16x8 __attribute__((ext_vector_type(8)));

__device__ __forceinline__ u16 f2bf(float f) {
  unsigned u = __builtin_bit_cast(unsigned, f);
  unsigned r = (u + 0x7fffu + ((u >> 16) & 1u)) >> 16;
  return (u16)r;
}
__device__ __forceinline__ u16 cvtbf(float f) {
  return __builtin_bit_cast(u16, __float2bfloat16(f));
}

#define GL_LDS16(gp, lp)                                                     \
  __builtin_amdgcn_global_load_lds((const __attribute__((address_space(1))) void*)(gp), \
                                   (__attribute__((address_space(3))) void*)(lp), 16, 0, 0)

// ================= cooperative precompute: B=AA^T, T_k inverses, blocked solve, Wf =================
__global__ __launch_bounds__(256) void k_pre(const float* __restrict__ A, float* __restrict__ B,
                                             float* __restrict__ P, float* __restrict__ Tm,
                                             float* __restrict__ rd2, u16* __restrict__ Wf) {
  cg::grid_group grid = cg::this_grid();
  __shared__ float s0[32][68], s1[32][68];
  __shared__ float Ct[64][68], Pb[64][68], Pu[64][68], Ts[64][68];
  const int tid = threadIdx.x;
  const int bid = blockIdx.x;
  const int tx = tid & 15, ty = tid >> 4;

  // ---------- Phase A: B = A * A^T ----------
  {
    const int i0 = (bid >> 4) * 64, j0 = (bid & 15) * 64;
    const int sr = tid >> 2, sc = (tid & 3) * 8;
    f32x4 acc[4];
#pragma unroll
    for (int q = 0; q < 4; ++q) acc[q] = {0.f, 0.f, 0.f, 0.f};
    for (int k0 = 0; k0 < 1024; k0 += 32) {
      f32x4 a0 = *(const f32x4*)&A[(size_t)(i0 + sr) * 1024 + k0 + sc];
      f32x4 a1 = *(const f32x4*)&A[(size_t)(i0 + sr) * 1024 + k0 + sc + 4];
      f32x4 b0 = *(const f32x4*)&A[(size_t)(j0 + sr) * 1024 + k0 + sc];
      f32x4 b1 = *(const f32x4*)&A[(size_t)(j0 + sr) * 1024 + k0 + sc + 4];
      __syncthreads();
#pragma unroll
      for (int q = 0; q < 4; ++q) {
        s0[sc + q][sr] = a0[q]; s0[sc + 4 + q][sr] = a1[q];
        s1[sc + q][sr] = b0[q]; s1[sc + 4 + q][sr] = b1[q];
      }
      __syncthreads();
#pragma unroll
      for (int kk = 0; kk < 32; ++kk) {
        f32x4 av = *(const f32x4*)&s0[kk][ty * 4];
        f32x4 bv = *(const f32x4*)&s1[kk][tx * 4];
#pragma unroll
        for (int q = 0; q < 4; ++q) acc[q] += bv * av[q];
      }
    }
#pragma unroll
    for (int q = 0; q < 4; ++q)
      *(f32x4*)&B[(size_t)(i0 + ty * 4 + q) * 1024 + j0 + tx * 4] = acc[q];
  }
  grid.sync();

  // ---------- Phase B: 16 parallel diag-block inverses T_k = (I+L_kk)^-1, plus global rd2 ----------
  if (bid < 16) {
    const int k0 = bid * 64;
    if (tid < 64) Pb[0][tid] = 2.0f / B[(size_t)(k0 + tid) * 1025];
    __syncthreads();
    {
      const int i = tid >> 2, j0q = (tid & 3) * 16;
#pragma unroll
      for (int jj = 0; jj < 16; ++jj) {
        int j = j0q + jj;
        Ct[i][j] = (j > i) ? B[(size_t)(k0 + i) * 1024 + k0 + j] * Pb[0][j] : 0.0f;
      }
    }
    __syncthreads();
    if (tid < 64) {
      float pc[64];
#pragma unroll
      for (int r = 0; r < 64; ++r) pc[r] = (r == tid) ? 1.0f : 0.0f;
#pragma unroll
      for (int i = 0; i < 63; ++i) {
        const float pi = pc[i];
#pragma unroll
        for (int j = i + 1; j < 64; ++j) pc[j] -= Ct[i][j] * pi;
      }
#pragma unroll
      for (int r = 0; r < 64; ++r) Tm[(size_t)bid * 4096 + r * 64 + tid] = pc[r];
    }
  } else if (bid < 20) {
    int i = (bid - 16) * 256 + tid;
    rd2[i] = 2.0f / B[(size_t)i * 1025];
  }
  grid.sync();

  // ---------- Phase C: 16 stages, lazy right-looking; solve replaced by T_k GEMM-apply ----------
  for (int k = 0; k < 16; ++k) {
    const int nact = (16 - k) * 16;
    if (bid < nact) {
      const int rb = k + (bid >> 4), cb = bid & 15, n0 = cb * 64;
      f32x4 acc[4];
#pragma unroll
      for (int q = 0; q < 4; ++q) acc[q] = {0.f, 0.f, 0.f, 0.f};
      if (k > 0) {
        const int s = k - 1;
        const int sr = tid >> 2, sc = (tid & 3) * 16;
        const float r2 = rd2[rb * 64 + sr];
        const float* bsrc = &B[(size_t)(rb * 64 + sr) * 1024 + s * 64 + sc];
        const float* psrc = &P[(size_t)(s * 64 + sr) * 1024 + n0 + sc];
#pragma unroll
        for (int q = 0; q < 4; ++q) {
          f32x4 v = *(const f32x4*)(bsrc + q * 4);
          *(f32x4*)&Ct[sr][sc + q * 4] = v * r2;
          *(f32x4*)&Pb[sr][sc + q * 4] = *(const f32x4*)(psrc + q * 4);
        }
        __syncthreads();
#pragma unroll 8
        for (int i = 0; i < 64; ++i) {
          f32x4 pv = *(const f32x4*)&Pb[i][tx * 4];
#pragma unroll
          for (int q = 0; q < 4; ++q) acc[q] += pv * Ct[ty * 4 + q][i];
        }
      }
      if (rb == k) {
        if (k > 0) {
#pragma unroll
          for (int q = 0; q < 4; ++q) {
            f32x4 old = *(const f32x4*)&P[(size_t)(k * 64 + ty * 4 + q) * 1024 + n0 + tx * 4];
            *(f32x4*)&Pu[ty * 4 + q][tx * 4] = old - acc[q];
          }
        } else {
          const int sr = tid >> 2, sc = (tid & 3) * 16;
#pragma unroll
          for (int q = 0; q < 4; ++q)
            *(f32x4*)&Pu[sr][sc + q * 4] = *(const f32x4*)&P[(size_t)sr * 1024 + n0 + sc + q * 4];
        }
        {
          const int trr = tid >> 2, tq = (tid & 3) * 16;
#pragma unroll
          for (int q2 = 0; q2 < 16; ++q2)
            Ts[tq + q2][trr] = Tm[(size_t)k * 4096 + (size_t)trr * 64 + tq + q2];
        }
        __syncthreads();
        f32x4 a2[4];
#pragma unroll
        for (int q = 0; q < 4; ++q) a2[q] = {0.f, 0.f, 0.f, 0.f};
#pragma unroll 8
        for (int i = 0; i < 64; ++i) {
          f32x4 uv = *(const f32x4*)&Pu[i][tx * 4];
          f32x4 tv = *(const f32x4*)&Ts[i][ty * 4];
#pragma unroll
          for (int q = 0; q < 4; ++q) a2[q] += uv * tv[q];
        }
#pragma unroll
        for (int q = 0; q < 4; ++q)
          *(f32x4*)&P[(size_t)(k * 64 + ty * 4 + q) * 1024 + n0 + tx * 4] = a2[q];
      } else {
#pragma unroll
        for (int q = 0; q < 4; ++q) {
          f32x4* dst = (f32x4*)&P[(size_t)(rb * 64 + ty * 4 + q) * 1024 + n0 + tx * 4];
          *dst = *dst - acc[q];
        }
      }
    }
    grid.sync();
  }

  // ---------- Phase D: Wf (fragment order) ----------
  {
    const int kb = (bid >> 4) * 64, nb2 = (bid & 15) * 64;
    const int sr = tid >> 3, sc = (tid & 7) * 8;
    f32x4 acc[4];
#pragma unroll
    for (int q = 0; q < 4; ++q) acc[q] = {0.f, 0.f, 0.f, 0.f};
    for (int i0 = 0; i0 < 1024; i0 += 32) {
      float r2 = rd2[i0 + sr];
      f32x4 a0 = *(const f32x4*)&A[(size_t)(i0 + sr) * 1024 + kb + sc];
      f32x4 a1 = *(const f32x4*)&A[(size_t)(i0 + sr) * 1024 + kb + sc + 4];
      f32x4 p0 = *(const f32x4*)&P[(size_t)(i0 + sr) * 1024 + nb2 + sc];
      f32x4 p1 = *(const f32x4*)&P[(size_t)(i0 + sr) * 1024 + nb2 + sc + 4];
      __syncthreads();
      *(f32x4*)&s0[sr][sc]     = a0 * r2;
      *(f32x4*)&s0[sr][sc + 4] = a1 * r2;
      *(f32x4*)&s1[sr][sc]     = p0;
      *(f32x4*)&s1[sr][sc + 4] = p1;
      __syncthreads();
#pragma unroll
      for (int i = 0; i < 32; ++i) {
        f32x4 av = *(const f32x4*)&s0[i][ty * 4];
        f32x4 pv = *(const f32x4*)&s1[i][tx * 4];
#pragma unroll
        for (int q = 0; q < 4; ++q) acc[q] += pv * av[q];
      }
    }
    const int ktile = (kb + ty * 4) >> 5;
    const int kg = ((ty * 4) >> 3) & 3;
    const int e0 = (ty * 4) & 7;
#pragma unroll
    for (int j = 0; j < 4; ++j) {
      int n = nb2 + tx * 4 + j;
      int nt = n >> 4;
      int ln = kg * 16 + (n & 15);
      u16x4 pk;
#pragma unroll
      for (int q = 0; q < 4; ++q) {
        int kk = kb + ty * 4 + q;
        float w = ((kk == n) ? 1.0f : 0.0f) - acc[q][j];
        pk[q] = f2bf(w);
      }
      *(u16x4*)&Wf[((size_t)(ktile * 64 + nt) * 64 + ln) * 8 + e0] = pk;
    }
  }
}

// ================= X fp32 -> bf16 in A-fragment order =================
__global__ __launch_bounds__(256) void k_xbf(const float* __restrict__ X, u16* __restrict__ Xbf) {
  const int gid = blockIdx.x * 256 + threadIdx.x;
  const int t = gid >> 10, w = gid & 1023;
  const int f = w >> 6, lane = w & 63;
  const int m = (t >> 4) * 128 + (f & 7) * 16 + (lane & 15);
  const int k = (t & 15) * 64 + (f >> 3) * 32 + (lane >> 4) * 8;
  const float* s = X + (size_t)m * 1024 + k;
  f32x4 u = *(const f32x4*)s;
  f32x4 v = *(const f32x4*)(s + 4);
  u16x8 h;
  h[0] = cvtbf(u[0]); h[1] = cvtbf(u[1]); h[2] = cvtbf(u[2]); h[3] = cvtbf(u[3]);
  h[4] = cvtbf(v[0]); h[5] = cvtbf(v[1]); h[6] = cvtbf(v[2]); h[7] = cvtbf(v[3]);
  *(u16x8*)(Xbf + (size_t)gid * 8) = h;
}

// ================= big GEMM: both operands via global_load_lds, fragment order =================
__global__ __launch_bounds__(256) void k_out_g(const u16* __restrict__ Xbf, const u16* __restrict__ Wf,
                                               const float* __restrict__ bvec, float* __restrict__ out) {
  __shared__ u16 As[8192];
  __shared__ u16 Bs[8192];
  const int tid = threadIdx.x;
  const int lane = tid & 63, wid = tid >> 6;
  const int wr = wid >> 1, wc = wid & 1;
  const int lin = blockIdx.x;
  const int mi = (lin & 7) * 64 + (lin >> 6);      // XCD-chunked
  const int ni = (lin >> 3) & 7;
  const long m0 = (long)mi * 128;
  const int n0 = ni * 128;

  const u16* ax = Xbf + (size_t)mi * 131072 + tid * 8;
  const u16* wsrc0 = Wf + (size_t)ni * 4096 + tid * 8;
  u16* asd = As + tid * 8;
  u16* bsd = Bs + tid * 8;
  const char* Ab = (const char*)As + lane * 16;
  const char* Bb = (const char*)Bs + lane * 16;

  f32x4 acc[4][4];
#pragma unroll
  for (int m = 0; m < 4; ++m)
#pragma unroll
    for (int n = 0; n < 4; ++n) acc[m][n] = {0.f, 0.f, 0.f, 0.f};

  for (int it = 0; it < 16; ++it) {
    const u16* a0 = ax + it * 8192;
    const u16* w0 = wsrc0 + (size_t)it * 65536;
    GL_LDS16(a0,        asd);
    GL_LDS16(a0 + 2048, asd + 2048);
    GL_LDS16(a0 + 4096, asd + 4096);
    GL_LDS16(a0 + 6144, asd + 6144);
    GL_LDS16(w0,         bsd);
    GL_LDS16(w0 + 2048,  bsd + 2048);
    GL_LDS16(w0 + 32768, bsd + 4096);
    GL_LDS16(w0 + 34816, bsd + 6144);
    __syncthreads();
#pragma unroll
    for (int kt2 = 0; kt2 < 2; ++kt2) {
      s16x8 af[4], bfr[4];
#pragma unroll
      for (int m = 0; m < 4; ++m) af[m] = *(const s16x8*)(Ab + ((kt2 * 8 + wr * 4 + m) << 10));
#pragma unroll
      for (int n = 0; n < 4; ++n) bfr[n] = *(const s16x8*)(Bb + ((kt2 * 8 + wc * 4 + n) << 10));
#pragma unroll
      for (int m = 0; m < 4; ++m)
#pragma unroll
        for (int n = 0; n < 4; ++n)
          acc[m][n] = __builtin_amdgcn_mfma_f32_16x16x32_bf16(af[m], bfr[n], acc[m][n], 0, 0, 0);
    }
    __syncthreads();
  }

  const long orow0 = m0 + wr * 64 + (lane >> 4) * 4;
  const int  ocol0 = n0 + wc * 64 + (lane & 15);
#pragma unroll
  for (int n = 0; n < 4; ++n) {
    const int cc = ocol0 + n * 16;
    const float bb = bvec[cc];
#pragma unroll
    for (int m = 0; m < 4; ++m) {
      const long r = orow0 + m * 16;
#pragma unroll
      for (int q = 0; q < 4; ++q)
        out[(r + q) * 1024 + cc] = acc[m][n][q] + bb;
    }
  }
}

// ================= fallback GEMM (reg-staged A) if workspace too small for Xbf =================
__global__ __launch_bounds__(256) void k_out_r(const float* __restrict__ X, const u16* __restrict__ Wf,
                                               const float* __restrict__ bvec, float* __restrict__ out) {
  __shared__ u16 As[8192];
  __shared__ u16 Bs[8192];
  const int tid = threadIdx.x;
  const int lane = tid & 63, wid = tid >> 6;
  const int wr = wid >> 1, wc = wid & 1;
  const int lin = blockIdx.x;
  const int mi = (lin & 7) * 64 + (lin >> 6);
  const int ni = (lin >> 3) & 7;
  const long m0 = (long)mi * 128;
  const int n0 = ni * 128;

  const float *xs0, *xs1, *xs2, *xs3;
  int aw0, aw1, aw2, aw3;
#define APREP(J, XS, AW) { int c = (J) * 256 + tid; int m = c >> 3, kg8 = c & 7;       \
    XS = X + (m0 + m) * 1024 + kg8 * 8;                                                \
    int kt2 = kg8 >> 2, ks = kg8 & 3, msub = m >> 4, mm = m & 15;                      \
    AW = (((kt2 * 8 + msub) * 64 + ks * 16 + mm) * 16) ^ (ks << 4); }
  APREP(0, xs0, aw0) APREP(1, xs1, aw1) APREP(2, xs2, aw2) APREP(3, xs3, aw3)
#undef APREP

  const u16* wsrc0 = Wf + (size_t)ni * 4096 + tid * 8;
  u16* bd0 = Bs + tid * 8;
  const int aro = (lane * 16) ^ (((lane >> 4) & 3) << 4);
  const char* Ab = (const char*)As + aro;
  const char* Bb = (const char*)Bs + lane * 16;

  f32x4 acc[4][4];
#pragma unroll
  for (int m = 0; m < 4; ++m)
#pragma unroll
    for (int n = 0; n < 4; ++n) acc[m][n] = {0.f, 0.f, 0.f, 0.f};

  for (int it = 0; it < 16; ++it) {
    const u16* w0 = wsrc0 + (size_t)it * 65536;
    GL_LDS16(w0,          bd0);
    GL_LDS16(w0 + 2048,   bd0 + 2048);
    GL_LDS16(w0 + 32768,  bd0 + 4096);
    GL_LDS16(w0 + 34816,  bd0 + 6144);
    const int ko = it * 64;
#define ASTAGE(XS, AW) { f32x4 u = *(const f32x4*)((XS) + ko); f32x4 v = *(const f32x4*)((XS) + ko + 4); \
    u16x8 h;                                                                              \
    h[0] = cvtbf(u[0]); h[1] = cvtbf(u[1]); h[2] = cvtbf(u[2]); h[3] = cvtbf(u[3]);       \
    h[4] = cvtbf(v[0]); h[5] = cvtbf(v[1]); h[6] = cvtbf(v[2]); h[7] = cvtbf(v[3]);       \
    *(u16x8*)((char*)As + (AW)) = h; }
    ASTAGE(xs0, aw0) ASTAGE(xs1, aw1) ASTAGE(xs2, aw2) ASTAGE(xs3, aw3)
#undef ASTAGE
    __syncthreads();
#pragma unroll
    for (int kt2 = 0; kt2 < 2; ++kt2) {
      s16x8 af[4], bfr[4];
#pragma unroll
      for (int m = 0; m < 4; ++m) af[m] = *(const s16x8*)(Ab + ((kt2 * 8 + wr * 4 + m) << 10));
#pragma unroll
      for (int n = 0; n < 4; ++n) bfr[n] = *(const s16x8*)(Bb + ((kt2 * 8 + wc * 4 + n) << 10));
#pragma unroll
      for (int m = 0; m < 4; ++m)
#pragma unroll
        for (int n = 0; n < 4; ++n)
          acc[m][n] = __builtin_amdgcn_mfma_f32_16x16x32_bf16(af[m], bfr[n], acc[m][n], 0, 0, 0);
    }
    __syncthreads();
  }

  const long orow0 = m0 + wr * 64 + (lane >> 4) * 4;
  const int  ocol0 = n0 + wc * 64 + (lane & 15);
#pragma unroll
  for (int n = 0; n < 4; ++n) {
    const int cc = ocol0 + n * 16;
    const float bb = bvec[cc];
#pragma unroll
    for (int m = 0; m < 4; ++m) {
      const long r = orow0 + m * 16;
#pragma unroll
      for (int q = 0; q < 4; ++q)
        out[(r + q) * 1024 + cc] = acc[m][n][q] + bb;
    }
  }
}

extern "C" void kernel_launch(void* const* d_in, const int* in_sizes, int n_in,
                              void* d_out, int out_size, void* d_ws, size_t ws_size,
                              hipStream_t stream) {
  const float* x  = (const float*)d_in[0];
  const float* A  = (const float*)d_in[1];
  const float* bv = (const float*)d_in[2];
  float* out = (float*)d_out;
  char* ws = (char*)d_ws;

  float* B   = (float*)(ws);                      // 4 MB
  float* P   = (float*)(ws + (4u << 20));         // 4 MB
  u16*   Wf  = (u16*)  (ws + (8u << 20));         // 2 MB
  float* rd2 = (float*)(ws + (10u << 20));        // 4 KB
  float* Tm  = (float*)(ws + (11u << 20));        // 256 KB
  u16*   Xbf = (u16*)  (ws + (12u << 20));        // 128 MB (optional)

  hipMemcpyAsync(P, A, 1024 * 1024 * sizeof(float), hipMemcpyDeviceToDevice, stream);

  void* args[6] = {(void*)&A, (void*)&B, (void*)&P, (void*)&Tm, (void*)&rd2, (void*)&Wf};
  hipLaunchCooperativeKernel((void*)k_pre, dim3(256), dim3(256), args, 0, stream);

  const size_t need = (12u << 20) + (size_t)65536 * 1024 * 2;
  if (ws_size >= need) {
    k_xbf<<<32768, 256, 0, stream>>>(x, Xbf);
    k_out_g<<<4096, 256, 0, stream>>>(Xbf, Wf, bv, out);
  } else {
    k_out_r<<<4096, 256, 0, stream>>>(x, Wf, bv, out);
  }
}

// Round 4
// 606.900 us; speedup vs baseline: 1.7447x; 1.7447x over previous
//
#include <hip/hip_runtime.h>
#include <hip/hip_bf16.h>

typedef unsigned short u16;
typedef float f32x4 __attribute__((ext_vector_type(4)));
typedef u16   u16x8 __attribute__((ext_vector_type(8)));
typedef u16   u16x4 __attribute__((ext_vector_type(4)));
typedef short s16x8 __attribute__((ext_vector_type(8)));

__device__ __forceinline__ u16 f2bf(float f) {
  unsigned u = __builtin_bit_cast(unsigned, f);
  unsigned r = (u + 0x7fffu + ((u >> 16) & 1u)) >> 16;
  return (u16)r;
}
__device__ __forceinline__ u16 cvtbf(float f) {
  return __builtin_bit_cast(u16, __float2bfloat16(f));
}

#define GL_LDS16(gp, lp)                                                     \
  __builtin_amdgcn_global_load_lds((const __attribute__((address_space(1))) void*)(gp), \
                                   (__attribute__((address_space(3))) void*)(lp), 16, 0, 0)

// ================= B = A * A^T (fp32, 64x64 tiles) =================
__global__ __launch_bounds__(256) void k_bbt(const float* __restrict__ A, float* __restrict__ B) {
  __shared__ float s0[32][68];
  __shared__ float s1[32][68];
  const int tid = threadIdx.x;
  const int i0 = blockIdx.y * 64, j0 = blockIdx.x * 64;
  const int tx = tid & 15, ty = tid >> 4;
  const int sr = tid >> 2, sc = (tid & 3) * 8;
  f32x4 acc[4];
#pragma unroll
  for (int q = 0; q < 4; ++q) acc[q] = {0.f, 0.f, 0.f, 0.f};

  for (int k0 = 0; k0 < 1024; k0 += 32) {
    f32x4 a0 = *(const f32x4*)&A[(size_t)(i0 + sr) * 1024 + k0 + sc];
    f32x4 a1 = *(const f32x4*)&A[(size_t)(i0 + sr) * 1024 + k0 + sc + 4];
    f32x4 b0 = *(const f32x4*)&A[(size_t)(j0 + sr) * 1024 + k0 + sc];
    f32x4 b1 = *(const f32x4*)&A[(size_t)(j0 + sr) * 1024 + k0 + sc + 4];
    __syncthreads();
#pragma unroll
    for (int q = 0; q < 4; ++q) {
      s0[sc + q][sr] = a0[q]; s0[sc + 4 + q][sr] = a1[q];
      s1[sc + q][sr] = b0[q]; s1[sc + 4 + q][sr] = b1[q];
    }
    __syncthreads();
#pragma unroll
    for (int kk = 0; kk < 32; ++kk) {
      f32x4 av = *(const f32x4*)&s0[kk][ty * 4];
      f32x4 bv = *(const f32x4*)&s1[kk][tx * 4];
#pragma unroll
      for (int q = 0; q < 4; ++q) acc[q] += bv * av[q];
    }
  }
#pragma unroll
  for (int q = 0; q < 4; ++q)
    *(f32x4*)&B[(size_t)(i0 + ty * 4 + q) * 1024 + j0 + tx * 4] = acc[q];
}

// ================= diag-block inverses T_k -> M diagonal; blocks 16..19: rd2 =================
__global__ __launch_bounds__(256) void k_tinv(const float* __restrict__ B, float* __restrict__ M,
                                              float* __restrict__ rd2) {
  __shared__ float Ct[64][68];
  __shared__ float rdl[64];
  const int tid = threadIdx.x;
  const int bid = blockIdx.x;
  if (bid >= 16) {
    int i = (bid - 16) * 256 + tid;
    rd2[i] = 2.0f / B[(size_t)i * 1025];
    return;
  }
  const int k0 = bid * 64;
  if (tid < 64) rdl[tid] = 2.0f / B[(size_t)(k0 + tid) * 1025];
  __syncthreads();
  {
    const int i = tid >> 2, j0q = (tid & 3) * 16;
#pragma unroll
    for (int jj = 0; jj < 16; ++jj) {
      int j = j0q + jj;
      Ct[i][j] = (j > i) ? B[(size_t)(k0 + i) * 1024 + k0 + j] * rdl[j] : 0.0f;
    }
  }
  __syncthreads();
  if (tid < 64) {
    float pc[64];
#pragma unroll
    for (int r = 0; r < 64; ++r) pc[r] = (r == tid) ? 1.0f : 0.0f;
#pragma unroll
    for (int i = 0; i < 63; ++i) {
      const float pi = pc[i];
#pragma unroll
      for (int j = i + 1; j < 64; ++j) pc[j] -= Ct[i][j] * pi;
    }
#pragma unroll
    for (int r = 0; r < 64; ++r) M[(size_t)(k0 + r) * 1024 + k0 + tid] = pc[r];
  }
}

// ================= level GEMM 1: U_p = Cscaled[a+s:a+2s, a:a+s] * M[a:a+s, a:a+s] =================
__global__ __launch_bounds__(256) void k_u(const float* __restrict__ B, const float* __restrict__ rd2,
                                           const float* __restrict__ M, float* __restrict__ U, int lvl) {
  __shared__ float sA[32][68];
  __shared__ float sB[32][68];
  const int tid = threadIdx.x;
  const int s = 64 << lvl;
  const int ti = blockIdx.x >> lvl, tj = blockIdx.x & ((1 << lvl) - 1);
  const int a = blockIdx.y * (s << 1);
  const int m0 = a + s + ti * 64;
  const int n0 = a + tj * 64;
  const int tx = tid & 15, ty = tid >> 4;
  const int asr = tid >> 2, asc = (tid & 3) * 8;
  const int bkr = tid >> 3, bnc = (tid & 7) * 8;
  const float r2 = rd2[m0 + asr];
  f32x4 acc[4];
#pragma unroll
  for (int q = 0; q < 4; ++q) acc[q] = {0.f, 0.f, 0.f, 0.f};

  for (int k0 = 0; k0 < s; k0 += 32) {
    f32x4 a0 = *(const f32x4*)&B[(size_t)(m0 + asr) * 1024 + a + k0 + asc];
    f32x4 a1 = *(const f32x4*)&B[(size_t)(m0 + asr) * 1024 + a + k0 + asc + 4];
    f32x4 b0 = *(const f32x4*)&M[(size_t)(a + k0 + bkr) * 1024 + n0 + bnc];
    f32x4 b1 = *(const f32x4*)&M[(size_t)(a + k0 + bkr) * 1024 + n0 + bnc + 4];
    a0 *= r2; a1 *= r2;
    __syncthreads();
#pragma unroll
    for (int q = 0; q < 4; ++q) { sA[asc + q][asr] = a0[q]; sA[asc + 4 + q][asr] = a1[q]; }
    *(f32x4*)&sB[bkr][bnc] = b0;
    *(f32x4*)&sB[bkr][bnc + 4] = b1;
    __syncthreads();
#pragma unroll
    for (int kk = 0; kk < 32; ++kk) {
      f32x4 av = *(const f32x4*)&sA[kk][ty * 4];
      f32x4 bv = *(const f32x4*)&sB[kk][tx * 4];
#pragma unroll
      for (int q = 0; q < 4; ++q) acc[q] += bv * av[q];
    }
  }
  float* up = U + (size_t)blockIdx.y * s * s;
#pragma unroll
  for (int q = 0; q < 4; ++q)
    *(f32x4*)&up[(size_t)(ti * 64 + ty * 4 + q) * s + tj * 64 + tx * 4] = acc[q];
}

// ================= level GEMM 2: M[a+s:a+2s, a:a+s] = - M[a+s:a+2s, a+s:a+2s] * U_p =================
__global__ __launch_bounds__(256) void k_moff(float* __restrict__ M, const float* __restrict__ U, int lvl) {
  __shared__ float sA[32][68];
  __shared__ float sB[32][68];
  const int tid = threadIdx.x;
  const int s = 64 << lvl;
  const int ti = blockIdx.x >> lvl, tj = blockIdx.x & ((1 << lvl) - 1);
  const int a = blockIdx.y * (s << 1);
  const int m0 = a + s + ti * 64;
  const int n0 = a + tj * 64;
  const int tx = tid & 15, ty = tid >> 4;
  const int asr = tid >> 2, asc = (tid & 3) * 8;
  const int bkr = tid >> 3, bnc = (tid & 7) * 8;
  const float* up = U + (size_t)blockIdx.y * s * s;
  f32x4 acc[4];
#pragma unroll
  for (int q = 0; q < 4; ++q) acc[q] = {0.f, 0.f, 0.f, 0.f};

  for (int k0 = 0; k0 < s; k0 += 32) {
    f32x4 a0 = *(const f32x4*)&M[(size_t)(m0 + asr) * 1024 + a + s + k0 + asc];
    f32x4 a1 = *(const f32x4*)&M[(size_t)(m0 + asr) * 1024 + a + s + k0 + asc + 4];
    f32x4 b0 = *(const f32x4*)&up[(size_t)(k0 + bkr) * s + tj * 64 + bnc];
    f32x4 b1 = *(const f32x4*)&up[(size_t)(k0 + bkr) * s + tj * 64 + bnc + 4];
    __syncthreads();
#pragma unroll
    for (int q = 0; q < 4; ++q) { sA[asc + q][asr] = a0[q]; sA[asc + 4 + q][asr] = a1[q]; }
    *(f32x4*)&sB[bkr][bnc] = b0;
    *(f32x4*)&sB[bkr][bnc + 4] = b1;
    __syncthreads();
#pragma unroll
    for (int kk = 0; kk < 32; ++kk) {
      f32x4 av = *(const f32x4*)&sA[kk][ty * 4];
      f32x4 bv = *(const f32x4*)&sB[kk][tx * 4];
#pragma unroll
      for (int q = 0; q < 4; ++q) acc[q] += bv * av[q];
    }
  }
#pragma unroll
  for (int q = 0; q < 4; ++q)
    *(f32x4*)&M[(size_t)(m0 + ty * 4 + q) * 1024 + n0 + tx * 4] = -acc[q];
}

// ================= Y = M * A (triangular K-skip) =================
__global__ __launch_bounds__(256) void k_yma(const float* __restrict__ M, const float* __restrict__ A,
                                             float* __restrict__ Y) {
  __shared__ float sA[32][68];
  __shared__ float sB[32][68];
  const int tid = threadIdx.x;
  const int ri = blockIdx.y, cj = blockIdx.x;
  const int m0 = ri * 64, n0 = cj * 64;
  const int kmax = (ri + 1) * 64;
  const int tx = tid & 15, ty = tid >> 4;
  const int asr = tid >> 2, asc = (tid & 3) * 8;
  const int bkr = tid >> 3, bnc = (tid & 7) * 8;
  f32x4 acc[4];
#pragma unroll
  for (int q = 0; q < 4; ++q) acc[q] = {0.f, 0.f, 0.f, 0.f};

  for (int k0 = 0; k0 < kmax; k0 += 32) {
    f32x4 a0 = *(const f32x4*)&M[(size_t)(m0 + asr) * 1024 + k0 + asc];
    f32x4 a1 = *(const f32x4*)&M[(size_t)(m0 + asr) * 1024 + k0 + asc + 4];
    f32x4 b0 = *(const f32x4*)&A[(size_t)(k0 + bkr) * 1024 + n0 + bnc];
    f32x4 b1 = *(const f32x4*)&A[(size_t)(k0 + bkr) * 1024 + n0 + bnc + 4];
    __syncthreads();
#pragma unroll
    for (int q = 0; q < 4; ++q) { sA[asc + q][asr] = a0[q]; sA[asc + 4 + q][asr] = a1[q]; }
    *(f32x4*)&sB[bkr][bnc] = b0;
    *(f32x4*)&sB[bkr][bnc + 4] = b1;
    __syncthreads();
#pragma unroll
    for (int kk = 0; kk < 32; ++kk) {
      f32x4 av = *(const f32x4*)&sA[kk][ty * 4];
      f32x4 bv = *(const f32x4*)&sB[kk][tx * 4];
#pragma unroll
      for (int q = 0; q < 4; ++q) acc[q] += bv * av[q];
    }
  }
#pragma unroll
  for (int q = 0; q < 4; ++q)
    *(f32x4*)&Y[(size_t)(m0 + ty * 4 + q) * 1024 + n0 + tx * 4] = acc[q];
}

// ================= Wf in MFMA-B-fragment order =================
__global__ __launch_bounds__(256) void k_w(const float* __restrict__ A, const float* __restrict__ P,
                                           const float* __restrict__ rd2, u16* __restrict__ Wf) {
  __shared__ float As[32][68];
  __shared__ float Ps[32][68];
  const int tid = threadIdx.x;
  const int kb = blockIdx.y * 64, nb = blockIdx.x * 64;
  const int sr = tid >> 3, sc = (tid & 7) * 8;
  const int tx = tid & 15, ty = tid >> 4;
  f32x4 acc[4];
#pragma unroll
  for (int q = 0; q < 4; ++q) acc[q] = {0.f, 0.f, 0.f, 0.f};

  for (int i0 = 0; i0 < 1024; i0 += 32) {
    float r2 = rd2[i0 + sr];
    f32x4 a0 = *(const f32x4*)&A[(size_t)(i0 + sr) * 1024 + kb + sc];
    f32x4 a1 = *(const f32x4*)&A[(size_t)(i0 + sr) * 1024 + kb + sc + 4];
    f32x4 p0 = *(const f32x4*)&P[(size_t)(i0 + sr) * 1024 + nb + sc];
    f32x4 p1 = *(const f32x4*)&P[(size_t)(i0 + sr) * 1024 + nb + sc + 4];
    __syncthreads();
    *(f32x4*)&As[sr][sc]     = a0 * r2;
    *(f32x4*)&As[sr][sc + 4] = a1 * r2;
    *(f32x4*)&Ps[sr][sc]     = p0;
    *(f32x4*)&Ps[sr][sc + 4] = p1;
    __syncthreads();
#pragma unroll
    for (int i = 0; i < 32; ++i) {
      f32x4 av = *(const f32x4*)&As[i][ty * 4];
      f32x4 pv = *(const f32x4*)&Ps[i][tx * 4];
#pragma unroll
      for (int q = 0; q < 4; ++q) acc[q] += pv * av[q];
    }
  }
  const int ktile = (kb + ty * 4) >> 5;
  const int kg = ((ty * 4) >> 3) & 3;
  const int e0 = (ty * 4) & 7;
#pragma unroll
  for (int j = 0; j < 4; ++j) {
    int n = nb + tx * 4 + j;
    int nt = n >> 4;
    int ln = kg * 16 + (n & 15);
    u16x4 pk;
#pragma unroll
    for (int q = 0; q < 4; ++q) {
      int kk = kb + ty * 4 + q;
      float w = ((kk == n) ? 1.0f : 0.0f) - acc[q][j];
      pk[q] = f2bf(w);
    }
    *(u16x4*)&Wf[((size_t)(ktile * 64 + nt) * 64 + ln) * 8 + e0] = pk;
  }
}

// ================= X fp32 -> bf16 in A-fragment order =================
__global__ __launch_bounds__(256) void k_xbf(const float* __restrict__ X, u16* __restrict__ Xbf) {
  const int gid = blockIdx.x * 256 + threadIdx.x;
  const int t = gid >> 10, w = gid & 1023;
  const int f = w >> 6, lane = w & 63;
  const int m = (t >> 4) * 128 + (f & 7) * 16 + (lane & 15);
  const int k = (t & 15) * 64 + (f >> 3) * 32 + (lane >> 4) * 8;
  const float* s = X + (size_t)m * 1024 + k;
  f32x4 u = *(const f32x4*)s;
  f32x4 v = *(const f32x4*)(s + 4);
  u16x8 h;
  h[0] = cvtbf(u[0]); h[1] = cvtbf(u[1]); h[2] = cvtbf(u[2]); h[3] = cvtbf(u[3]);
  h[4] = cvtbf(v[0]); h[5] = cvtbf(v[1]); h[6] = cvtbf(v[2]); h[7] = cvtbf(v[3]);
  *(u16x8*)(Xbf + (size_t)gid * 8) = h;
}

// ================= big GEMM: both operands via global_load_lds, fragment order =================
__global__ __launch_bounds__(256) void k_out_g(const u16* __restrict__ Xbf, const u16* __restrict__ Wf,
                                               const float* __restrict__ bvec, float* __restrict__ out) {
  __shared__ u16 As[8192];
  __shared__ u16 Bs[8192];
  const int tid = threadIdx.x;
  const int lane = tid & 63, wid = tid >> 6;
  const int wr = wid >> 1, wc = wid & 1;
  const int lin = blockIdx.x;
  const int mi = (lin & 7) * 64 + (lin >> 6);      // XCD-chunked
  const int ni = (lin >> 3) & 7;
  const long m0 = (long)mi * 128;
  const int n0 = ni * 128;

  const u16* ax = Xbf + (size_t)mi * 131072 + tid * 8;
  const u16* wsrc0 = Wf + (size_t)ni * 4096 + tid * 8;
  u16* asd = As + tid * 8;
  u16* bsd = Bs + tid * 8;
  const char* Ab = (const char*)As + lane * 16;
  const char* Bb = (const char*)Bs + lane * 16;

  f32x4 acc[4][4];
#pragma unroll
  for (int m = 0; m < 4; ++m)
#pragma unroll
    for (int n = 0; n < 4; ++n) acc[m][n] = {0.f, 0.f, 0.f, 0.f};

  for (int it = 0; it < 16; ++it) {
    const u16* a0 = ax + it * 8192;
    const u16* w0 = wsrc0 + (size_t)it * 65536;
    GL_LDS16(a0,        asd);
    GL_LDS16(a0 + 2048, asd + 2048);
    GL_LDS16(a0 + 4096, asd + 4096);
    GL_LDS16(a0 + 6144, asd + 6144);
    GL_LDS16(w0,         bsd);
    GL_LDS16(w0 + 2048,  bsd + 2048);
    GL_LDS16(w0 + 32768, bsd + 4096);
    GL_LDS16(w0 + 34816, bsd + 6144);
    __syncthreads();
#pragma unroll
    for (int kt2 = 0; kt2 < 2; ++kt2) {
      s16x8 af[4], bfr[4];
#pragma unroll
      for (int m = 0; m < 4; ++m) af[m] = *(const s16x8*)(Ab + ((kt2 * 8 + wr * 4 + m) << 10));
#pragma unroll
      for (int n = 0; n < 4; ++n) bfr[n] = *(const s16x8*)(Bb + ((kt2 * 8 + wc * 4 + n) << 10));
#pragma unroll
      for (int m = 0; m < 4; ++m)
#pragma unroll
        for (int n = 0; n < 4; ++n)
          acc[m][n] = __builtin_amdgcn_mfma_f32_16x16x32_bf16(af[m], bfr[n], acc[m][n], 0, 0, 0);
    }
    __syncthreads();
  }

  const long orow0 = m0 + wr * 64 + (lane >> 4) * 4;
  const int  ocol0 = n0 + wc * 64 + (lane & 15);
#pragma unroll
  for (int n = 0; n < 4; ++n) {
    const int cc = ocol0 + n * 16;
    const float bb = bvec[cc];
#pragma unroll
    for (int m = 0; m < 4; ++m) {
      const long r = orow0 + m * 16;
#pragma unroll
      for (int q = 0; q < 4; ++q)
        out[(r + q) * 1024 + cc] = acc[m][n][q] + bb;
    }
  }
}

// ================= fallback GEMM (reg-staged A) if workspace too small for Xbf =================
__global__ __launch_bounds__(256) void k_out_r(const float* __restrict__ X, const u16* __restrict__ Wf,
                                               const float* __restrict__ bvec, float* __restrict__ out) {
  __shared__ u16 As[8192];
  __shared__ u16 Bs[8192];
  const int tid = threadIdx.x;
  const int lane = tid & 63, wid = tid >> 6;
  const int wr = wid >> 1, wc = wid & 1;
  const int lin = blockIdx.x;
  const int mi = (lin & 7) * 64 + (lin >> 6);
  const int ni = (lin >> 3) & 7;
  const long m0 = (long)mi * 128;
  const int n0 = ni * 128;

  const float *xs0, *xs1, *xs2, *xs3;
  int aw0, aw1, aw2, aw3;
#define APREP(J, XS, AW) { int c = (J) * 256 + tid; int m = c >> 3, kg8 = c & 7;       \
    XS = X + (m0 + m) * 1024 + kg8 * 8;                                                \
    int kt2 = kg8 >> 2, ks = kg8 & 3, msub = m >> 4, mm = m & 15;                      \
    AW = (((kt2 * 8 + msub) * 64 + ks * 16 + mm) * 16) ^ (ks << 4); }
  APREP(0, xs0, aw0) APREP(1, xs1, aw1) APREP(2, xs2, aw2) APREP(3, xs3, aw3)
#undef APREP

  const u16* wsrc0 = Wf + (size_t)ni * 4096 + tid * 8;
  u16* bd0 = Bs + tid * 8;
  const int aro = (lane * 16) ^ (((lane >> 4) & 3) << 4);
  const char* Ab = (const char*)As + aro;
  const char* Bb = (const char*)Bs + lane * 16;

  f32x4 acc[4][4];
#pragma unroll
  for (int m = 0; m < 4; ++m)
#pragma unroll
    for (int n = 0; n < 4; ++n) acc[m][n] = {0.f, 0.f, 0.f, 0.f};

  for (int it = 0; it < 16; ++it) {
    const u16* w0 = wsrc0 + (size_t)it * 65536;
    GL_LDS16(w0,          bd0);
    GL_LDS16(w0 + 2048,   bd0 + 2048);
    GL_LDS16(w0 + 32768,  bd0 + 4096);
    GL_LDS16(w0 + 34816,  bd0 + 6144);
    const int ko = it * 64;
#define ASTAGE(XS, AW) { f32x4 u = *(const f32x4*)((XS) + ko); f32x4 v = *(const f32x4*)((XS) + ko + 4); \
    u16x8 h;                                                                              \
    h[0] = cvtbf(u[0]); h[1] = cvtbf(u[1]); h[2] = cvtbf(u[2]); h[3] = cvtbf(u[3]);       \
    h[4] = cvtbf(v[0]); h[5] = cvtbf(v[1]); h[6] = cvtbf(v[2]); h[7] = cvtbf(v[3]);       \
    *(u16x8*)((char*)As + (AW)) = h; }
    ASTAGE(xs0, aw0) ASTAGE(xs1, aw1) ASTAGE(xs2, aw2) ASTAGE(xs3, aw3)
#undef ASTAGE
    __syncthreads();
#pragma unroll
    for (int kt2 = 0; kt2 < 2; ++kt2) {
      s16x8 af[4], bfr[4];
#pragma unroll
      for (int m = 0; m < 4; ++m) af[m] = *(const s16x8*)(Ab + ((kt2 * 8 + wr * 4 + m) << 10));
#pragma unroll
      for (int n = 0; n < 4; ++n) bfr[n] = *(const s16x8*)(Bb + ((kt2 * 8 + wc * 4 + n) << 10));
#pragma unroll
      for (int m = 0; m < 4; ++m)
#pragma unroll
        for (int n = 0; n < 4; ++n)
          acc[m][n] = __builtin_amdgcn_mfma_f32_16x16x32_bf16(af[m], bfr[n], acc[m][n], 0, 0, 0);
    }
    __syncthreads();
  }

  const long orow0 = m0 + wr * 64 + (lane >> 4) * 4;
  const int  ocol0 = n0 + wc * 64 + (lane & 15);
#pragma unroll
  for (int n = 0; n < 4; ++n) {
    const int cc = ocol0 + n * 16;
    const float bb = bvec[cc];
#pragma unroll
    for (int m = 0; m < 4; ++m) {
      const long r = orow0 + m * 16;
#pragma unroll
      for (int q = 0; q < 4; ++q)
        out[(r + q) * 1024 + cc] = acc[m][n][q] + bb;
    }
  }
}

extern "C" void kernel_launch(void* const* d_in, const int* in_sizes, int n_in,
                              void* d_out, int out_size, void* d_ws, size_t ws_size,
                              hipStream_t stream) {
  const float* x  = (const float*)d_in[0];
  const float* A  = (const float*)d_in[1];
  const float* bv = (const float*)d_in[2];
  float* out = (float*)d_out;
  char* ws = (char*)d_ws;

  // Layout (Y aliases B: B dead after last k_moff):
  float* B   = (float*)(ws);                              // 4 MB, becomes Y
  float* Y   = B;
  float* M   = (float*)(ws + (4u << 20));                 // 4 MB
  u16*   Wf  = (u16*)  (ws + (8u << 20));                 // 2 MB
  float* rd2 = (float*)(ws + (10u << 20));                // 4 KB
  float* U   = (float*)(ws + (10u << 20) + 65536);        // 1 MB (used only pre-Y)
  u16*   Xbf = (u16*)  (ws + (12u << 20));                // 128 MB

  hipMemsetAsync(M, 0, 1024 * 1024 * sizeof(float), stream);  // zeros for upper-tri blocks
  k_bbt<<<dim3(16, 16), 256, 0, stream>>>(A, B);
  k_tinv<<<20, 256, 0, stream>>>(B, M, rd2);
  for (int lvl = 0; lvl < 4; ++lvl) {
    const int nt2 = 1 << (2 * lvl);      // tiles per pair
    const int np  = 8 >> lvl;            // pairs
    k_u<<<dim3(nt2, np), 256, 0, stream>>>(B, rd2, M, U, lvl);
    k_moff<<<dim3(nt2, np), 256, 0, stream>>>(M, U, lvl);
  }
  k_yma<<<dim3(16, 16), 256, 0, stream>>>(M, A, Y);
  k_w<<<dim3(16, 16), 256, 0, stream>>>(A, Y, rd2, Wf);

  const size_t need = (12u << 20) + (size_t)65536 * 1024 * 2;
  if (ws_size >= need) {
    k_xbf<<<32768, 256, 0, stream>>>(x, Xbf);
    k_out_g<<<4096, 256, 0, stream>>>(Xbf, Wf, bv, out);
  } else {
    k_out_r<<<4096, 256, 0, stream>>>(x, Wf, bv, out);
  }
}

// Round 5
// 572.690 us; speedup vs baseline: 1.8490x; 1.0597x over previous
//
#include <hip/hip_runtime.h>
#include <hip/hip_bf16.h>

typedef unsigned short u16;
typedef float f32x4 __attribute__((ext_vector_type(4)));
typedef u16   u16x8 __attribute__((ext_vector_type(8)));
typedef u16   u16x4 __attribute__((ext_vector_type(4)));
typedef short s16x8 __attribute__((ext_vector_type(8)));

__device__ __forceinline__ u16 f2bf(float f) {
  unsigned u = __builtin_bit_cast(unsigned, f);
  unsigned r = (u + 0x7fffu + ((u >> 16) & 1u)) >> 16;
  return (u16)r;
}
__device__ __forceinline__ u16 cvtbf(float f) {
  return __builtin_bit_cast(u16, __float2bfloat16(f));
}

#define GL_LDS16(gp, lp)                                                     \
  __builtin_amdgcn_global_load_lds((const __attribute__((address_space(1))) void*)(gp), \
                                   (__attribute__((address_space(3))) void*)(lp), 16, 0, 0)

// ================= B = A * A^T (fp32, 64x64 tiles) =================
__global__ __launch_bounds__(256) void k_bbt(const float* __restrict__ A, float* __restrict__ B) {
  __shared__ float s0[32][68];
  __shared__ float s1[32][68];
  const int tid = threadIdx.x;
  const int i0 = blockIdx.y * 64, j0 = blockIdx.x * 64;
  const int tx = tid & 15, ty = tid >> 4;
  const int sr = tid >> 2, sc = (tid & 3) * 8;
  f32x4 acc[4];
#pragma unroll
  for (int q = 0; q < 4; ++q) acc[q] = {0.f, 0.f, 0.f, 0.f};

  for (int k0 = 0; k0 < 1024; k0 += 32) {
    f32x4 a0 = *(const f32x4*)&A[(size_t)(i0 + sr) * 1024 + k0 + sc];
    f32x4 a1 = *(const f32x4*)&A[(size_t)(i0 + sr) * 1024 + k0 + sc + 4];
    f32x4 b0 = *(const f32x4*)&A[(size_t)(j0 + sr) * 1024 + k0 + sc];
    f32x4 b1 = *(const f32x4*)&A[(size_t)(j0 + sr) * 1024 + k0 + sc + 4];
    __syncthreads();
#pragma unroll
    for (int q = 0; q < 4; ++q) {
      s0[sc + q][sr] = a0[q]; s0[sc + 4 + q][sr] = a1[q];
      s1[sc + q][sr] = b0[q]; s1[sc + 4 + q][sr] = b1[q];
    }
    __syncthreads();
#pragma unroll
    for (int kk = 0; kk < 32; ++kk) {
      f32x4 av = *(const f32x4*)&s0[kk][ty * 4];
      f32x4 bv = *(const f32x4*)&s1[kk][tx * 4];
#pragma unroll
      for (int q = 0; q < 4; ++q) acc[q] += bv * av[q];
    }
  }
#pragma unroll
  for (int q = 0; q < 4; ++q)
    *(f32x4*)&B[(size_t)(i0 + ty * 4 + q) * 1024 + j0 + tx * 4] = acc[q];
}

// ================= diag-block inverses T_k -> M diagonal; blocks 16..19: rd2 =================
__global__ __launch_bounds__(256) void k_tinv(const float* __restrict__ B, float* __restrict__ M,
                                              float* __restrict__ rd2) {
  __shared__ float Ct[64][68];
  __shared__ float rdl[64];
  const int tid = threadIdx.x;
  const int bid = blockIdx.x;
  if (bid >= 16) {
    int i = (bid - 16) * 256 + tid;
    rd2[i] = 2.0f / B[(size_t)i * 1025];
    return;
  }
  const int k0 = bid * 64;
  if (tid < 64) rdl[tid] = 2.0f / B[(size_t)(k0 + tid) * 1025];
  __syncthreads();
  {
    const int i = tid >> 2, j0q = (tid & 3) * 16;
#pragma unroll
    for (int jj = 0; jj < 16; ++jj) {
      int j = j0q + jj;
      Ct[i][j] = (j > i) ? B[(size_t)(k0 + i) * 1024 + k0 + j] * rdl[j] : 0.0f;
    }
  }
  __syncthreads();
  if (tid < 64) {
    float pc[64];
#pragma unroll
    for (int r = 0; r < 64; ++r) pc[r] = (r == tid) ? 1.0f : 0.0f;
#pragma unroll
    for (int i = 0; i < 63; ++i) {
      const float pi = pc[i];
#pragma unroll
      for (int j = i + 1; j < 64; ++j) pc[j] -= Ct[i][j] * pi;
    }
#pragma unroll
    for (int r = 0; r < 64; ++r) M[(size_t)(k0 + r) * 1024 + k0 + tid] = pc[r];
  }
}

// ================= level GEMM 1: U_p = Cscaled[a+s:a+2s, a:a+s] * M[a:a+s, a:a+s] =================
__global__ __launch_bounds__(256) void k_u(const float* __restrict__ B, const float* __restrict__ rd2,
                                           const float* __restrict__ M, float* __restrict__ U, int lvl) {
  __shared__ float sA[32][68];
  __shared__ float sB[32][68];
  const int tid = threadIdx.x;
  const int s = 64 << lvl;
  const int ti = blockIdx.x >> lvl, tj = blockIdx.x & ((1 << lvl) - 1);
  const int a = blockIdx.y * (s << 1);
  const int m0 = a + s + ti * 64;
  const int n0 = a + tj * 64;
  const int tx = tid & 15, ty = tid >> 4;
  const int asr = tid >> 2, asc = (tid & 3) * 8;
  const int bkr = tid >> 3, bnc = (tid & 7) * 8;
  const float r2 = rd2[m0 + asr];
  f32x4 acc[4];
#pragma unroll
  for (int q = 0; q < 4; ++q) acc[q] = {0.f, 0.f, 0.f, 0.f};

  for (int k0 = 0; k0 < s; k0 += 32) {
    f32x4 a0 = *(const f32x4*)&B[(size_t)(m0 + asr) * 1024 + a + k0 + asc];
    f32x4 a1 = *(const f32x4*)&B[(size_t)(m0 + asr) * 1024 + a + k0 + asc + 4];
    f32x4 b0 = *(const f32x4*)&M[(size_t)(a + k0 + bkr) * 1024 + n0 + bnc];
    f32x4 b1 = *(const f32x4*)&M[(size_t)(a + k0 + bkr) * 1024 + n0 + bnc + 4];
    a0 *= r2; a1 *= r2;
    __syncthreads();
#pragma unroll
    for (int q = 0; q < 4; ++q) { sA[asc + q][asr] = a0[q]; sA[asc + 4 + q][asr] = a1[q]; }
    *(f32x4*)&sB[bkr][bnc] = b0;
    *(f32x4*)&sB[bkr][bnc + 4] = b1;
    __syncthreads();
#pragma unroll
    for (int kk = 0; kk < 32; ++kk) {
      f32x4 av = *(const f32x4*)&sA[kk][ty * 4];
      f32x4 bv = *(const f32x4*)&sB[kk][tx * 4];
#pragma unroll
      for (int q = 0; q < 4; ++q) acc[q] += bv * av[q];
    }
  }
  float* up = U + (size_t)blockIdx.y * s * s;
#pragma unroll
  for (int q = 0; q < 4; ++q)
    *(f32x4*)&up[(size_t)(ti * 64 + ty * 4 + q) * s + tj * 64 + tx * 4] = acc[q];
}

// ================= level GEMM 2: M[a+s:a+2s, a:a+s] = - M[a+s:a+2s, a+s:a+2s] * U_p =================
__global__ __launch_bounds__(256) void k_moff(float* __restrict__ M, const float* __restrict__ U, int lvl) {
  __shared__ float sA[32][68];
  __shared__ float sB[32][68];
  const int tid = threadIdx.x;
  const int s = 64 << lvl;
  const int ti = blockIdx.x >> lvl, tj = blockIdx.x & ((1 << lvl) - 1);
  const int a = blockIdx.y * (s << 1);
  const int m0 = a + s + ti * 64;
  const int n0 = a + tj * 64;
  const int tx = tid & 15, ty = tid >> 4;
  const int asr = tid >> 2, asc = (tid & 3) * 8;
  const int bkr = tid >> 3, bnc = (tid & 7) * 8;
  const float* up = U + (size_t)blockIdx.y * s * s;
  f32x4 acc[4];
#pragma unroll
  for (int q = 0; q < 4; ++q) acc[q] = {0.f, 0.f, 0.f, 0.f};

  for (int k0 = 0; k0 < s; k0 += 32) {
    f32x4 a0 = *(const f32x4*)&M[(size_t)(m0 + asr) * 1024 + a + s + k0 + asc];
    f32x4 a1 = *(const f32x4*)&M[(size_t)(m0 + asr) * 1024 + a + s + k0 + asc + 4];
    f32x4 b0 = *(const f32x4*)&up[(size_t)(k0 + bkr) * s + tj * 64 + bnc];
    f32x4 b1 = *(const f32x4*)&up[(size_t)(k0 + bkr) * s + tj * 64 + bnc + 4];
    __syncthreads();
#pragma unroll
    for (int q = 0; q < 4; ++q) { sA[asc + q][asr] = a0[q]; sA[asc + 4 + q][asr] = a1[q]; }
    *(f32x4*)&sB[bkr][bnc] = b0;
    *(f32x4*)&sB[bkr][bnc + 4] = b1;
    __syncthreads();
#pragma unroll
    for (int kk = 0; kk < 32; ++kk) {
      f32x4 av = *(const f32x4*)&sA[kk][ty * 4];
      f32x4 bv = *(const f32x4*)&sB[kk][tx * 4];
#pragma unroll
      for (int q = 0; q < 4; ++q) acc[q] += bv * av[q];
    }
  }
#pragma unroll
  for (int q = 0; q < 4; ++q)
    *(f32x4*)&M[(size_t)(m0 + ty * 4 + q) * 1024 + n0 + tx * 4] = -acc[q];
}

// ================= Y = M * A (triangular K-skip) =================
__global__ __launch_bounds__(256) void k_yma(const float* __restrict__ M, const float* __restrict__ A,
                                             float* __restrict__ Y) {
  __shared__ float sA[32][68];
  __shared__ float sB[32][68];
  const int tid = threadIdx.x;
  const int ri = blockIdx.y, cj = blockIdx.x;
  const int m0 = ri * 64, n0 = cj * 64;
  const int kmax = (ri + 1) * 64;
  const int tx = tid & 15, ty = tid >> 4;
  const int asr = tid >> 2, asc = (tid & 3) * 8;
  const int bkr = tid >> 3, bnc = (tid & 7) * 8;
  f32x4 acc[4];
#pragma unroll
  for (int q = 0; q < 4; ++q) acc[q] = {0.f, 0.f, 0.f, 0.f};

  for (int k0 = 0; k0 < kmax; k0 += 32) {
    f32x4 a0 = *(const f32x4*)&M[(size_t)(m0 + asr) * 1024 + k0 + asc];
    f32x4 a1 = *(const f32x4*)&M[(size_t)(m0 + asr) * 1024 + k0 + asc + 4];
    f32x4 b0 = *(const f32x4*)&A[(size_t)(k0 + bkr) * 1024 + n0 + bnc];
    f32x4 b1 = *(const f32x4*)&A[(size_t)(k0 + bkr) * 1024 + n0 + bnc + 4];
    __syncthreads();
#pragma unroll
    for (int q = 0; q < 4; ++q) { sA[asc + q][asr] = a0[q]; sA[asc + 4 + q][asr] = a1[q]; }
    *(f32x4*)&sB[bkr][bnc] = b0;
    *(f32x4*)&sB[bkr][bnc + 4] = b1;
    __syncthreads();
#pragma unroll
    for (int kk = 0; kk < 32; ++kk) {
      f32x4 av = *(const f32x4*)&sA[kk][ty * 4];
      f32x4 bv = *(const f32x4*)&sB[kk][tx * 4];
#pragma unroll
      for (int q = 0; q < 4; ++q) acc[q] += bv * av[q];
    }
  }
#pragma unroll
  for (int q = 0; q < 4; ++q)
    *(f32x4*)&Y[(size_t)(m0 + ty * 4 + q) * 1024 + n0 + tx * 4] = acc[q];
}

// ================= Wf in MFMA-B-fragment order =================
__global__ __launch_bounds__(256) void k_w(const float* __restrict__ A, const float* __restrict__ P,
                                           const float* __restrict__ rd2, u16* __restrict__ Wf) {
  __shared__ float As[32][68];
  __shared__ float Ps[32][68];
  const int tid = threadIdx.x;
  const int kb = blockIdx.y * 64, nb = blockIdx.x * 64;
  const int sr = tid >> 3, sc = (tid & 7) * 8;
  const int tx = tid & 15, ty = tid >> 4;
  f32x4 acc[4];
#pragma unroll
  for (int q = 0; q < 4; ++q) acc[q] = {0.f, 0.f, 0.f, 0.f};

  for (int i0 = 0; i0 < 1024; i0 += 32) {
    float r2 = rd2[i0 + sr];
    f32x4 a0 = *(const f32x4*)&A[(size_t)(i0 + sr) * 1024 + kb + sc];
    f32x4 a1 = *(const f32x4*)&A[(size_t)(i0 + sr) * 1024 + kb + sc + 4];
    f32x4 p0 = *(const f32x4*)&P[(size_t)(i0 + sr) * 1024 + nb + sc];
    f32x4 p1 = *(const f32x4*)&P[(size_t)(i0 + sr) * 1024 + nb + sc + 4];
    __syncthreads();
    *(f32x4*)&As[sr][sc]     = a0 * r2;
    *(f32x4*)&As[sr][sc + 4] = a1 * r2;
    *(f32x4*)&Ps[sr][sc]     = p0;
    *(f32x4*)&Ps[sr][sc + 4] = p1;
    __syncthreads();
#pragma unroll
    for (int i = 0; i < 32; ++i) {
      f32x4 av = *(const f32x4*)&As[i][ty * 4];
      f32x4 pv = *(const f32x4*)&Ps[i][tx * 4];
#pragma unroll
      for (int q = 0; q < 4; ++q) acc[q] += pv * av[q];
    }
  }
  const int ktile = (kb + ty * 4) >> 5;
  const int kg = ((ty * 4) >> 3) & 3;
  const int e0 = (ty * 4) & 7;
#pragma unroll
  for (int j = 0; j < 4; ++j) {
    int n = nb + tx * 4 + j;
    int nt = n >> 4;
    int ln = kg * 16 + (n & 15);
    u16x4 pk;
#pragma unroll
    for (int q = 0; q < 4; ++q) {
      int kk = kb + ty * 4 + q;
      float w = ((kk == n) ? 1.0f : 0.0f) - acc[q][j];
      pk[q] = f2bf(w);
    }
    *(u16x4*)&Wf[((size_t)(ktile * 64 + nt) * 64 + ln) * 8 + e0] = pk;
  }
}

// ================= X fp32 -> bf16, A-fragment order for 256-row M-tiles =================
// layout: [mi256][it(16)][kt2(2)][msub(16)][lane(64)][8]
__global__ __launch_bounds__(256) void k_xbf(const float* __restrict__ X, u16* __restrict__ Xbf) {
  const int gid = blockIdx.x * 256 + threadIdx.x;
  const int mi   = gid >> 15;
  const int it   = (gid >> 11) & 15;
  const int kt2  = (gid >> 10) & 1;
  const int msub = (gid >> 6) & 15;
  const int lane = gid & 63;
  const int m = mi * 256 + msub * 16 + (lane & 15);
  const int k = it * 64 + kt2 * 32 + (lane >> 4) * 8;
  const float* s = X + (size_t)m * 1024 + k;
  f32x4 u = *(const f32x4*)s;
  f32x4 v = *(const f32x4*)(s + 4);
  u16x8 h;
  h[0] = cvtbf(u[0]); h[1] = cvtbf(u[1]); h[2] = cvtbf(u[2]); h[3] = cvtbf(u[3]);
  h[4] = cvtbf(v[0]); h[5] = cvtbf(v[1]); h[6] = cvtbf(v[2]); h[7] = cvtbf(v[3]);
  *(u16x8*)(Xbf + (size_t)gid * 8) = h;
}

// ================= 256x256 pipelined GEMM: out = x @ W + b =================
// 8 waves (2M x 4N), BK=64, 2 LDS tile-buffers (128 KiB), 4 phases/K-tile,
// raw s_barrier + manual vmcnt (prefetch of tile t+1 overlaps compute of t).
__global__ __launch_bounds__(512, 2) void k_out8(const u16* __restrict__ Xbf, const u16* __restrict__ Wf,
                                                 const float* __restrict__ bvec, float* __restrict__ out) {
  __shared__ u16 As[32768];   // 2 x [kt2(2)][msub(16)][lane(64)][8]
  __shared__ u16 Bs[32768];   // 2 x [kt2(2)][nsub(16)][lane(64)][8]
  const int tid = threadIdx.x;
  const int lane = tid & 63, wid = tid >> 6;
  const int wr = wid >> 2, wc = wid & 3;          // 2M x 4N waves; per-wave out 128x64
  const int lin = blockIdx.x;
  const int xcd = lin & 7, idx = lin >> 3;
  const int mi = xcd * 32 + (idx >> 2);           // XCD-chunked; ni fastest among concurrent blocks
  const int ni = idx & 3;

  const u16* ax = Xbf + (size_t)mi * 262144;      // per (mi,it): 16384 elems
  const u16* wbase = Wf + (size_t)ni * 8192;      // per it: +65536; per kt2: +32768

  f32x4 acc[8][4];
#pragma unroll
  for (int m = 0; m < 8; ++m)
#pragma unroll
    for (int n = 0; n < 4; ++n) acc[m][n] = {0.f, 0.f, 0.f, 0.f};

  // stage unit u (0..3 = A quarters, 4..7 = B quarters) of tile `it` into buffer `buf`
#define STAGE_UNIT(u, it, buf) do {                                                          \
    if ((u) < 4) {                                                                           \
      GL_LDS16(ax + (size_t)(it) * 16384 + (u) * 4096 + tid * 8,                             \
               As + (buf) * 16384 + (u) * 4096 + tid * 8);                                   \
    } else {                                                                                 \
      const int v_ = (u) - 4;                                                                \
      GL_LDS16(wbase + (size_t)(it) * 65536 + (v_ >> 1) * 32768 + (v_ & 1) * 4096 + tid * 8, \
               Bs + (buf) * 16384 + (v_ >> 1) * 8192 + (v_ & 1) * 4096 + tid * 8);           \
    }                                                                                        \
  } while (0)

  // prologue: stage tile 0 fully
#pragma unroll
  for (int u = 0; u < 8; ++u) STAGE_UNIT(u, 0, 0);
  asm volatile("s_waitcnt vmcnt(0)" ::: "memory");
  __builtin_amdgcn_s_barrier();

  for (int t = 0; t < 16; ++t) {
    const int cur = t & 1;
    const u16* Asb = As + cur * 16384;
    const u16* Bsb = Bs + cur * 16384;
#pragma unroll
    for (int p = 0; p < 4; ++p) {
      const int mq = p & 1, nq = p >> 1;
      s16x8 af[2][4], bf_[2][2];
#pragma unroll
      for (int kt2 = 0; kt2 < 2; ++kt2) {
#pragma unroll
        for (int m = 0; m < 4; ++m)
          af[kt2][m] = *(const s16x8*)&Asb[(size_t)((kt2 << 4) + wr * 8 + mq * 4 + m) * 512 + lane * 8];
#pragma unroll
        for (int n = 0; n < 2; ++n)
          bf_[kt2][n] = *(const s16x8*)&Bsb[(size_t)((kt2 << 4) + wc * 4 + nq * 2 + n) * 512 + lane * 8];
      }
      if (t < 15) {  // prefetch tile t+1 into the other buffer: 3/3/2 units over phases 0-2
        if (p == 0) { STAGE_UNIT(0, t + 1, cur ^ 1); STAGE_UNIT(1, t + 1, cur ^ 1); STAGE_UNIT(4, t + 1, cur ^ 1); }
        else if (p == 1) { STAGE_UNIT(2, t + 1, cur ^ 1); STAGE_UNIT(3, t + 1, cur ^ 1); STAGE_UNIT(5, t + 1, cur ^ 1); }
        else if (p == 2) { STAGE_UNIT(6, t + 1, cur ^ 1); STAGE_UNIT(7, t + 1, cur ^ 1); }
      }
      __builtin_amdgcn_s_setprio(1);
#pragma unroll
      for (int m = 0; m < 4; ++m)
#pragma unroll
        for (int n = 0; n < 2; ++n) {
          acc[mq * 4 + m][nq * 2 + n] =
              __builtin_amdgcn_mfma_f32_16x16x32_bf16(af[0][m], bf_[0][n], acc[mq * 4 + m][nq * 2 + n], 0, 0, 0);
          acc[mq * 4 + m][nq * 2 + n] =
              __builtin_amdgcn_mfma_f32_16x16x32_bf16(af[1][m], bf_[1][n], acc[mq * 4 + m][nq * 2 + n], 0, 0, 0);
        }
      __builtin_amdgcn_s_setprio(0);
      if (p == 3 && t < 15) asm volatile("s_waitcnt vmcnt(0)" ::: "memory");  // drain tile t+1 (issued >=1 phase ago)
      __builtin_amdgcn_s_barrier();
    }
  }
#undef STAGE_UNIT

  const long orow0 = (long)mi * 256 + wr * 128 + (lane >> 4) * 4;
  const int  ocol0 = ni * 256 + wc * 64 + (lane & 15);
#pragma unroll
  for (int aj = 0; aj < 4; ++aj) {
    const int cc = ocol0 + aj * 16;
    const float bb = bvec[cc];
#pragma unroll
    for (int ai = 0; ai < 8; ++ai) {
      const long r = orow0 + ai * 16;
#pragma unroll
      for (int q = 0; q < 4; ++q)
        out[(r + q) * 1024 + cc] = acc[ai][aj][q] + bb;
    }
  }
}

// ================= fallback GEMM (reg-staged A) if workspace too small for Xbf =================
__global__ __launch_bounds__(256) void k_out_r(const float* __restrict__ X, const u16* __restrict__ Wf,
                                               const float* __restrict__ bvec, float* __restrict__ out) {
  __shared__ u16 As[8192];
  __shared__ u16 Bs[8192];
  const int tid = threadIdx.x;
  const int lane = tid & 63, wid = tid >> 6;
  const int wr = wid >> 1, wc = wid & 1;
  const int lin = blockIdx.x;
  const int mi = (lin & 7) * 64 + (lin >> 6);
  const int ni = (lin >> 3) & 7;
  const long m0 = (long)mi * 128;
  const int n0 = ni * 128;

  const float *xs0, *xs1, *xs2, *xs3;
  int aw0, aw1, aw2, aw3;
#define APREP(J, XS, AW) { int c = (J) * 256 + tid; int m = c >> 3, kg8 = c & 7;       \
    XS = X + (m0 + m) * 1024 + kg8 * 8;                                                \
    int kt2 = kg8 >> 2, ks = kg8 & 3, msub = m >> 4, mm = m & 15;                      \
    AW = (((kt2 * 8 + msub) * 64 + ks * 16 + mm) * 16) ^ (ks << 4); }
  APREP(0, xs0, aw0) APREP(1, xs1, aw1) APREP(2, xs2, aw2) APREP(3, xs3, aw3)
#undef APREP

  const u16* wsrc0 = Wf + (size_t)ni * 4096 + tid * 8;
  u16* bd0 = Bs + tid * 8;
  const int aro = (lane * 16) ^ (((lane >> 4) & 3) << 4);
  const char* Ab = (const char*)As + aro;
  const char* Bb = (const char*)Bs + lane * 16;

  f32x4 acc[4][4];
#pragma unroll
  for (int m = 0; m < 4; ++m)
#pragma unroll
    for (int n = 0; n < 4; ++n) acc[m][n] = {0.f, 0.f, 0.f, 0.f};

  for (int it = 0; it < 16; ++it) {
    const u16* w0 = wsrc0 + (size_t)it * 65536;
    GL_LDS16(w0,          bd0);
    GL_LDS16(w0 + 2048,   bd0 + 2048);
    GL_LDS16(w0 + 32768,  bd0 + 4096);
    GL_LDS16(w0 + 34816,  bd0 + 6144);
    const int ko = it * 64;
#define ASTAGE(XS, AW) { f32x4 u = *(const f32x4*)((XS) + ko); f32x4 v = *(const f32x4*)((XS) + ko + 4); \
    u16x8 h;                                                                              \
    h[0] = cvtbf(u[0]); h[1] = cvtbf(u[1]); h[2] = cvtbf(u[2]); h[3] = cvtbf(u[3]);       \
    h[4] = cvtbf(v[0]); h[5] = cvtbf(v[1]); h[6] = cvtbf(v[2]); h[7] = cvtbf(v[3]);       \
    *(u16x8*)((char*)As + (AW)) = h; }
    ASTAGE(xs0, aw0) ASTAGE(xs1, aw1) ASTAGE(xs2, aw2) ASTAGE(xs3, aw3)
#undef ASTAGE
    __syncthreads();
#pragma unroll
    for (int kt2 = 0; kt2 < 2; ++kt2) {
      s16x8 af[4], bfr[4];
#pragma unroll
      for (int m = 0; m < 4; ++m) af[m] = *(const s16x8*)(Ab + ((kt2 * 8 + wr * 4 + m) << 10));
#pragma unroll
      for (int n = 0; n < 4; ++n) bfr[n] = *(const s16x8*)(Bb + ((kt2 * 8 + wc * 4 + n) << 10));
#pragma unroll
      for (int m = 0; m < 4; ++m)
#pragma unroll
        for (int n = 0; n < 4; ++n)
          acc[m][n] = __builtin_amdgcn_mfma_f32_16x16x32_bf16(af[m], bfr[n], acc[m][n], 0, 0, 0);
    }
    __syncthreads();
  }

  const long orow0 = m0 + wr * 64 + (lane >> 4) * 4;
  const int  ocol0 = n0 + wc * 64 + (lane & 15);
#pragma unroll
  for (int n = 0; n < 4; ++n) {
    const int cc = ocol0 + n * 16;
    const float bb = bvec[cc];
#pragma unroll
    for (int m = 0; m < 4; ++m) {
      const long r = orow0 + m * 16;
#pragma unroll
      for (int q = 0; q < 4; ++q)
        out[(r + q) * 1024 + cc] = acc[m][n][q] + bb;
    }
  }
}

extern "C" void kernel_launch(void* const* d_in, const int* in_sizes, int n_in,
                              void* d_out, int out_size, void* d_ws, size_t ws_size,
                              hipStream_t stream) {
  const float* x  = (const float*)d_in[0];
  const float* A  = (const float*)d_in[1];
  const float* bv = (const float*)d_in[2];
  float* out = (float*)d_out;
  char* ws = (char*)d_ws;

  float* B   = (float*)(ws);                              // 4 MB, becomes Y
  float* Y   = B;
  float* M   = (float*)(ws + (4u << 20));                 // 4 MB
  u16*   Wf  = (u16*)  (ws + (8u << 20));                 // 2 MB
  float* rd2 = (float*)(ws + (10u << 20));                // 4 KB
  float* U   = (float*)(ws + (10u << 20) + 65536);        // 1 MB
  u16*   Xbf = (u16*)  (ws + (12u << 20));                // 128 MB

  hipMemsetAsync(M, 0, 1024 * 1024 * sizeof(float), stream);
  k_bbt<<<dim3(16, 16), 256, 0, stream>>>(A, B);
  k_tinv<<<20, 256, 0, stream>>>(B, M, rd2);
  for (int lvl = 0; lvl < 4; ++lvl) {
    const int nt2 = 1 << (2 * lvl);
    const int np  = 8 >> lvl;
    k_u<<<dim3(nt2, np), 256, 0, stream>>>(B, rd2, M, U, lvl);
    k_moff<<<dim3(nt2, np), 256, 0, stream>>>(M, U, lvl);
  }
  k_yma<<<dim3(16, 16), 256, 0, stream>>>(M, A, Y);
  k_w<<<dim3(16, 16), 256, 0, stream>>>(A, Y, rd2, Wf);

  const size_t need = (12u << 20) + (size_t)65536 * 1024 * 2;
  if (ws_size >= need) {
    k_xbf<<<32768, 256, 0, stream>>>(x, Xbf);
    k_out8<<<1024, 512, 0, stream>>>(Xbf, Wf, bv, out);
  } else {
    k_out_r<<<4096, 256, 0, stream>>>(x, Wf, bv, out);
  }
}